// Round 6
// baseline (281.790 us; speedup 1.0000x reference)
//
#include <hip/hip_runtime.h>

// EMA Vector Quantizer — R5 resubmit: M=2 rows-blocking + register prefetch + atomic-free.
// z: (32,64,64,64) fp32; w: (1024,64) fp32.
// Out flat: q (8388608) | loss (1) | commitment (1) | count (1024) | sum (65536)

#define HWsz   4096
#define Dd     64
#define Kk     1024
#define NB     32
#define NTOT   131072
#define QSIZE  (NTOT * Dd)
#define BETA_C 0.25f
#define DIST_BLOCKS 1024          // vq_dist grid (4 waves, 128 rows each)

typedef float  f32x4  __attribute__((ext_vector_type(4)));
typedef short  bf16x8 __attribute__((ext_vector_type(8)));

__device__ __forceinline__ unsigned short f2bf(float f) {
    unsigned u = __float_as_uint(f);
    u += 0x7FFF + ((u >> 16) & 1);
    return (unsigned short)(u >> 16);
}
__device__ __forceinline__ float bf2f(unsigned short b) {
    return __uint_as_float(((unsigned)b) << 16);
}

// ---------------- prep: c2 norms + codebook bf16 hi/lo split in B-frag layout ----
__global__ __launch_bounds__(256) void vq_prep(const float* __restrict__ w,
                                               float* __restrict__ c2,
                                               unsigned short* __restrict__ whi,
                                               unsigned short* __restrict__ wlo) {
    int t = blockIdx.x * 256 + threadIdx.x;           // 65536 threads
    int k = t >> 6, d = t & 63;
    float v = w[t];
    unsigned short hb = f2bf(v);
    unsigned short lb = f2bf(v - bf2f(hb));
    int ctile = k >> 4, col = k & 15;
    int s = d >> 5, kg = (d >> 3) & 3, j = d & 7;
    int idx = (((ctile * 2 + s) * 64) + kg * 16 + col) * 8 + j;
    whi[idx] = hb; wlo[idx] = lb;

    if (t < Kk) {
        const float4* c4 = reinterpret_cast<const float4*>(w + t * Dd);
        float s0 = 0.f, s1 = 0.f, s2 = 0.f, s3 = 0.f;
#pragma unroll
        for (int q = 0; q < 16; ++q) {
            float4 cq = c4[q];
            s0 = fmaf(cq.x, cq.x, s0); s1 = fmaf(cq.y, cq.y, s1);
            s2 = fmaf(cq.z, cq.z, s2); s3 = fmaf(cq.w, cq.w, s3);
        }
        c2[t] = (s0 + s1) + (s2 + s3);
    }
}

// ---------------- phase 1: distances, argmin, q, commitment, idx ----------------
// 1024 blocks x 4 waves; each wave owns 32 rows (2 row-tiles of 16).
__global__ __launch_bounds__(256, 4) void vq_dist(const float* __restrict__ z,
                                                  const float* __restrict__ w,
                                                  const float* __restrict__ c2,
                                                  const unsigned short* __restrict__ whi,
                                                  const unsigned short* __restrict__ wlo,
                                                  float* __restrict__ out,
                                                  float* __restrict__ commit_ws,
                                                  int* __restrict__ idx_ws) {
    const int lane = threadIdx.x & 63;
    const int wid  = threadIdx.x >> 6;
    const int b    = blockIdx.x >> 5;                  // 32 blocks per image
    const int t0   = (blockIdx.x & 31) * 8 + wid * 2;  // first of 2 row-tiles
    const int col  = lane & 15;
    const int kg   = lane >> 4;

    // ---- load 2 row-tiles' z, build bf16 hi/lo A-fragments ----
    bf16x8 zhi[2][2], zlo[2][2];
#pragma unroll
    for (int m = 0; m < 2; ++m) {
        const int hw0 = (t0 + m) << 4;
        const float* zbase = z + (size_t)b * (Dd * HWsz) + hw0 + col;
#pragma unroll
        for (int s = 0; s < 2; ++s) {
            bf16x8 h, l;
#pragma unroll
            for (int j = 0; j < 8; ++j) {
                float zz = zbase[(size_t)(32 * s + kg * 8 + j) * HWsz];
                unsigned short hb = f2bf(zz);
                unsigned short lb = f2bf(zz - bf2f(hb));
                h[j] = (short)hb; l[j] = (short)lb;
            }
            zhi[m][s] = h; zlo[m][s] = l;
        }
    }

    float best[2][4];
    int   bk[2][4];
#pragma unroll
    for (int m = 0; m < 2; ++m)
#pragma unroll
        for (int r = 0; r < 4; ++r) { best[m][r] = 3.4e38f; bk[m][r] = 0; }

    const bf16x8* ph = reinterpret_cast<const bf16x8*>(whi);
    const bf16x8* pl = reinterpret_cast<const bf16x8*>(wlo);

    // ---- software-prefetched scan over 64 code tiles ----
    bf16x8 h0 = ph[lane], h1 = ph[64 + lane];
    bf16x8 l0 = pl[lane], l1 = pl[64 + lane];
    float  cv = c2[col];

#pragma unroll 2
    for (int ct = 0; ct < 64; ++ct) {
        const int nx = (ct + 1) & 63;                  // wraps on last iter (harmless)
        bf16x8 nh0 = ph[(nx * 2 + 0) * 64 + lane];
        bf16x8 nh1 = ph[(nx * 2 + 1) * 64 + lane];
        bf16x8 nl0 = pl[(nx * 2 + 0) * 64 + lane];
        bf16x8 nl1 = pl[(nx * 2 + 1) * 64 + lane];
        float  ncv = c2[nx * 16 + col];

        const int kc = ct * 16 + col;
#pragma unroll
        for (int m = 0; m < 2; ++m) {
            // depth-3 + depth-3 accumulator chains
            f32x4 za = {0.f, 0.f, 0.f, 0.f};
            f32x4 zb = {0.f, 0.f, 0.f, 0.f};
            za = __builtin_amdgcn_mfma_f32_16x16x32_bf16(zhi[m][0], h0, za, 0, 0, 0);
            zb = __builtin_amdgcn_mfma_f32_16x16x32_bf16(zlo[m][0], h0, zb, 0, 0, 0);
            za = __builtin_amdgcn_mfma_f32_16x16x32_bf16(zhi[m][1], h1, za, 0, 0, 0);
            zb = __builtin_amdgcn_mfma_f32_16x16x32_bf16(zlo[m][1], h1, zb, 0, 0, 0);
            za = __builtin_amdgcn_mfma_f32_16x16x32_bf16(zhi[m][0], l0, za, 0, 0, 0);
            zb = __builtin_amdgcn_mfma_f32_16x16x32_bf16(zhi[m][1], l1, zb, 0, 0, 0);
#pragma unroll
            for (int r = 0; r < 4; ++r) {
                float s = fmaf(-2.f, za[r] + zb[r], cv);
                if (s < best[m][r]) { best[m][r] = s; bk[m][r] = kc; }
            }
        }
        h0 = nh0; h1 = nh1; l0 = nl0; l1 = nl1; cv = ncv;
    }

    // ---- merge argmin across the 16 code-column lanes ----
#pragma unroll
    for (int off = 1; off < 16; off <<= 1) {
#pragma unroll
        for (int m = 0; m < 2; ++m)
#pragma unroll
            for (int r = 0; r < 4; ++r) {
                float ob = __shfl_xor(best[m][r], off, 64);
                int   ok = __shfl_xor(bk[m][r],   off, 64);
                if (ob < best[m][r] || (ob == best[m][r] && ok < bk[m][r])) {
                    best[m][r] = ob; bk[m][r] = ok;
                }
            }
    }

    // ---- epilogue per row-tile ----
    float commit = 0.f;
    const int srcl = (col >> 2) << 4;
    const int rsel = col & 3;
#pragma unroll
    for (int m = 0; m < 2; ++m) {
        int c0 = __shfl(bk[m][0], srcl, 64);
        int c1 = __shfl(bk[m][1], srcl, 64);
        int c2r = __shfl(bk[m][2], srcl, 64);
        int c3 = __shfl(bk[m][3], srcl, 64);
        int mybk = (rsel == 0) ? c0 : (rsel == 1) ? c1 : (rsel == 2) ? c2r : c3;

        const int hw0 = (t0 + m) << 4;
        if (lane < 16) idx_ws[(size_t)b * HWsz + hw0 + col] = mybk;

        float* qbase = out + (size_t)b * (Dd * HWsz) + hw0 + col;
#pragma unroll
        for (int s = 0; s < 2; ++s) {
            const float4* cw = reinterpret_cast<const float4*>(w + mybk * Dd + 32 * s + kg * 8);
            float4 p0 = cw[0], p1 = cw[1];
            float cb[8] = {p0.x, p0.y, p0.z, p0.w, p1.x, p1.y, p1.z, p1.w};
#pragma unroll
            for (int j = 0; j < 8; ++j) {
                int   d  = 32 * s + kg * 8 + j;
                float zz = bf2f((unsigned short)zhi[m][s][j]) +
                           bf2f((unsigned short)zlo[m][s][j]);
                float cc = cb[j];
                qbase[(size_t)d * HWsz] = zz + (cc - zz);
                float dd = zz - cc;
                commit = fmaf(dd, dd, commit);
            }
        }
    }

#pragma unroll
    for (int off = 32; off > 0; off >>= 1) commit += __shfl_down(commit, off, 64);

    __shared__ float red[4];
    if (lane == 0) red[wid] = commit;
    __syncthreads();
    if (threadIdx.x == 0)
        commit_ws[blockIdx.x] = (red[0] + red[1]) + (red[2] + red[3]);   // no atomic
}

// ---------------- phase 2: per-(b, d-chunk, hw-quarter) LDS accumulation -------
// grid = NB * 8 * nq blocks.
__global__ __launch_bounds__(256) void vq_stats(const float* __restrict__ z,
                                                const int* __restrict__ idx_ws,
                                                float* __restrict__ psum,
                                                float* __restrict__ pcnt,
                                                int nq) {
    const int q     = blockIdx.x % nq;
    const int tmp   = blockIdx.x / nq;
    const int chunk = tmp & 7;
    const int b     = tmp >> 3;
    const int dbase = chunk * 8;
    const bool docnt = (chunk == 0);

    __shared__ float acc[8][Kk];
    __shared__ float cnt[Kk];
    for (int i = threadIdx.x; i < 8 * Kk; i += 256) acc[i >> 10][i & 1023] = 0.f;
    for (int i = threadIdx.x; i < Kk; i += 256) cnt[i] = 0.f;
    __syncthreads();

    const int pos4 = (HWsz / 4) / nq;                 // float4s per block
    const int4* ip = reinterpret_cast<const int4*>(idx_ws + (size_t)b * HWsz);
    for (int c = threadIdx.x; c < pos4; c += 256) {
        const int c4 = q * pos4 + c;
        int4 k4 = ip[c4];
#pragma unroll
        for (int d8 = 0; d8 < 8; ++d8) {
            const float4 v4 = reinterpret_cast<const float4*>(
                z + ((size_t)b * Dd + dbase + d8) * HWsz)[c4];
            atomicAdd(&acc[d8][k4.x], v4.x);
            atomicAdd(&acc[d8][k4.y], v4.y);
            atomicAdd(&acc[d8][k4.z], v4.z);
            atomicAdd(&acc[d8][k4.w], v4.w);
        }
        if (docnt) {
            atomicAdd(&cnt[k4.x], 1.f);
            atomicAdd(&cnt[k4.y], 1.f);
            atomicAdd(&cnt[k4.z], 1.f);
            atomicAdd(&cnt[k4.w], 1.f);
        }
    }
    __syncthreads();

    // psum layout: [(b*nq+q)][d][k]
    float* po = psum + ((size_t)(b * nq + q) * Dd + dbase) * Kk;
    for (int i = threadIdx.x; i < 8 * Kk; i += 256) po[i] = acc[i >> 10][i & 1023];
    if (docnt) {
        float* pc = pcnt + (size_t)(b * nq + q) * Kk;
        for (int i = threadIdx.x; i < Kk; i += 256) pc[i] = cnt[i];
    }
}

// ---------------- phase 3: reduce partials + losses ----------------
__global__ __launch_bounds__(256) void vq_reduce(const float* __restrict__ psum,
                                                 const float* __restrict__ pcnt,
                                                 const float* __restrict__ commit_ws,
                                                 float* __restrict__ out,
                                                 int nparts) {
    int t = blockIdx.x * 256 + threadIdx.x;   // 65536 threads (256 blocks)
    int k = t & 1023, d = t >> 10;
    float s = 0.f;
    for (int p = 0; p < nparts; ++p)
        s += psum[((size_t)p * Dd + d) * Kk + k];
    out[QSIZE + 2 + Kk + (size_t)k * Dd + d] = s;
    if (t < Kk) {
        float c = 0.f;
        for (int p = 0; p < nparts; ++p) c += pcnt[(size_t)p * Kk + t];
        out[QSIZE + 2 + t] = c;
    }

    if (blockIdx.x == 0) {
        float cs = 0.f;
        for (int i = threadIdx.x; i < DIST_BLOCKS; i += 256) cs += commit_ws[i];
#pragma unroll
        for (int off = 32; off > 0; off >>= 1) cs += __shfl_down(cs, off, 64);
        __shared__ float r2[4];
        const int lane = threadIdx.x & 63, wid = threadIdx.x >> 6;
        if (lane == 0) r2[wid] = cs;
        __syncthreads();
        if (threadIdx.x == 0) {
            float c = ((r2[0] + r2[1]) + (r2[2] + r2[3])) / (float)QSIZE;
            out[QSIZE]     = BETA_C * c;
            out[QSIZE + 1] = c;
        }
    }
}

extern "C" void kernel_launch(void* const* d_in, const int* in_sizes, int n_in,
                              void* d_out, int out_size, void* d_ws, size_t ws_size,
                              hipStream_t stream) {
    const float* z = (const float*)d_in[0];
    const float* w = (const float*)d_in[1];
    float* out = (float*)d_out;

    // ws layout (float offsets):
    // commit 0..1023 | c2 1024..2047 | whi (65536 us = 32768 f) | wlo | idx (131072 int)
    // | pcnt (NB*nq*1024) | psum (NB*nq*64*1024)
    float* commit_ws = (float*)d_ws;
    float* c2        = (float*)d_ws + 1024;
    unsigned short* whi = (unsigned short*)((float*)d_ws + 2048);
    unsigned short* wlo = whi + (Kk * Dd);
    int*   idx_ws = (int*)(wlo + (Kk * Dd));
    float* pcnt   = (float*)(idx_ws + NTOT);

    // pick spatial split factor by available workspace (constant across calls)
    size_t fixed_floats = 2048 + 65536 + 131072;      // commit+c2+wsplit+idx
    int nq = 4;
    size_t need4 = (fixed_floats + (size_t)NB * 4 * Kk + (size_t)NB * 4 * Dd * Kk) * 4;
    if (ws_size < need4) nq = 1;
    float* psum = pcnt + (size_t)NB * nq * Kk;

    vq_prep<<<(Kk * Dd) / 256, 256, 0, stream>>>(w, c2, whi, wlo);
    vq_dist<<<DIST_BLOCKS, 256, 0, stream>>>(z, w, c2, whi, wlo, out, commit_ws, idx_ws);
    vq_stats<<<NB * 8 * nq, 256, 0, stream>>>(z, idx_ws, psum, pcnt, nq);
    vq_reduce<<<(Kk * Dd) / 256, 256, 0, stream>>>(psum, pcnt, commit_ws, out, NB * nq);
}

// Round 7
// 236.133 us; speedup vs baseline: 1.1934x; 1.1934x over previous
//
#include <hip/hip_runtime.h>

// EMA Vector Quantizer — R7: LDS-staged fragment stream (global_load_lds dbuf),
// M=4 rows-blocking, dense atomic-free stats.
// z: (32,64,64,64) fp32; w: (1024,64) fp32.
// Out flat: q (8388608) | loss (1) | commitment (1) | count (1024) | sum (65536)

#define HWsz   4096
#define Dd     64
#define Kk     1024
#define NB     32
#define NTOT   131072
#define QSIZE  (NTOT * Dd)
#define BETA_C 0.25f
#define DIST_BLOCKS 1024
#define NCHUNK 16                 // 64 ct-tiles / 4 per chunk

typedef float  f32x4  __attribute__((ext_vector_type(4)));
typedef short  bf16x8 __attribute__((ext_vector_type(8)));

__device__ __forceinline__ unsigned short f2bf(float f) {
    unsigned u = __float_as_uint(f);
    u += 0x7FFF + ((u >> 16) & 1);
    return (unsigned short)(u >> 16);
}
__device__ __forceinline__ float bf2f(unsigned short b) {
    return __uint_as_float(((unsigned)b) << 16);
}

// async global->LDS 16B: lds = wave-uniform base (HW adds lane*16), g = per-lane addr
__device__ __forceinline__ void stage16(const void* g, void* lds, int lane) {
#if __has_builtin(__builtin_amdgcn_global_load_lds)
    __builtin_amdgcn_global_load_lds(
        (const __attribute__((address_space(1))) unsigned int*)g,
        (__attribute__((address_space(3))) unsigned int*)lds, 16, 0, 0);
#else
    *(bf16x8*)((unsigned short*)lds + lane * 8) = *(const bf16x8*)g;
#endif
}

// ---------------- prep: c2 norms + codebook bf16 hi/lo split (B-frag layout) ----
__global__ __launch_bounds__(256) void vq_prep(const float* __restrict__ w,
                                               float* __restrict__ c2,
                                               unsigned short* __restrict__ whi,
                                               unsigned short* __restrict__ wlo) {
    int t = blockIdx.x * 256 + threadIdx.x;           // 65536 threads
    int k = t >> 6, d = t & 63;
    float v = w[t];
    unsigned short hb = f2bf(v);
    unsigned short lb = f2bf(v - bf2f(hb));
    int ctile = k >> 4, col = k & 15;
    int s = d >> 5, kg = (d >> 3) & 3, j = d & 7;
    int idx = (((ctile * 2 + s) * 64) + kg * 16 + col) * 8 + j;
    whi[idx] = hb; wlo[idx] = lb;

    if (t < Kk) {
        const float4* c4 = reinterpret_cast<const float4*>(w + t * Dd);
        float s0 = 0.f, s1 = 0.f, s2 = 0.f, s3 = 0.f;
#pragma unroll
        for (int q = 0; q < 16; ++q) {
            float4 cq = c4[q];
            s0 = fmaf(cq.x, cq.x, s0); s1 = fmaf(cq.y, cq.y, s1);
            s2 = fmaf(cq.z, cq.z, s2); s3 = fmaf(cq.w, cq.w, s3);
        }
        c2[t] = (s0 + s1) + (s2 + s3);
    }
}

// ---------------- phase 1: distances, argmin, q, commitment, idx ----------------
// 1024 blocks x 2 waves; each wave owns 64 rows (4 row-tiles of 16).
// Codebook fragments stream through double-buffered LDS chunks of 4 ct-tiles.
__global__ __launch_bounds__(128, 3) void vq_dist(const float* __restrict__ z,
                                                  const float* __restrict__ w,
                                                  const float* __restrict__ c2,
                                                  const unsigned short* __restrict__ whi,
                                                  const unsigned short* __restrict__ wlo,
                                                  float* __restrict__ out,
                                                  float* __restrict__ commit_ws,
                                                  int* __restrict__ idx_ws) {
    const int lane = threadIdx.x & 63;
    const int wid  = threadIdx.x >> 6;                 // 0..1
    const int b    = blockIdx.x >> 5;                  // 32 blocks per image
    const int hwb  = (blockIdx.x & 31) * 128 + wid * 64; // wave's first row
    const int col  = lane & 15;
    const int kg   = lane >> 4;

    __shared__ unsigned short lbuf[2][8192];           // 2 x 16 KB

    // ---- build A fragments for 4 row-tiles (hi/lo bf16 split) ----
    bf16x8 zhi[4][2], zlo[4][2];
#pragma unroll
    for (int m = 0; m < 4; ++m) {
        const float* zbase = z + (size_t)b * (Dd * HWsz) + (hwb + m * 16) + col;
#pragma unroll
        for (int s = 0; s < 2; ++s) {
            bf16x8 h, l;
#pragma unroll
            for (int j = 0; j < 8; ++j) {
                float zz = zbase[(size_t)(32 * s + kg * 8 + j) * HWsz];
                unsigned short hb = f2bf(zz);
                unsigned short lb = f2bf(zz - bf2f(hb));
                h[j] = (short)hb; l[j] = (short)lb;
            }
            zhi[m][s] = h; zlo[m][s] = l;
        }
    }

    // staging: chunk c = 4 ct-tiles; per tile 4 KB as [wh0|wh1|wl0|wl1] x 1KB.
    // wave wid stages slot s=wid of tile rd (hi) and slot 2+wid (lo).
    const char* ghi = (const char*)whi;
    const char* glo = (const char*)wlo;
#define STAGE(c, bufi)                                                          \
    {                                                                           \
        unsigned short* dst = lbuf[bufi];                                       \
        _Pragma("unroll")                                                       \
        for (int rd = 0; rd < 4; ++rd) {                                        \
            int rec = ((c) * 8 + rd * 2 + wid) * 1024 + lane * 16;              \
            stage16(ghi + rec, dst + rd * 2048 + wid * 512, lane);              \
            stage16(glo + rec, dst + rd * 2048 + (2 + wid) * 512, lane);        \
        }                                                                       \
    }

    float best[4][4];
    int   bk[4][4];
#pragma unroll
    for (int m = 0; m < 4; ++m)
#pragma unroll
        for (int r = 0; r < 4; ++r) { best[m][r] = 3.4e38f; bk[m][r] = 0; }

    STAGE(0, 0);
    __syncthreads();

    for (int c = 0; c < NCHUNK; ++c) {
        const unsigned short* cb = lbuf[c & 1];
        if (c + 1 < NCHUNK) STAGE(c + 1, (c + 1) & 1);
#pragma unroll
        for (int t = 0; t < 4; ++t) {
            const int ct = c * 4 + t;
            bf16x8 wh0 = *(const bf16x8*)(cb + t * 2048 + 0 * 512 + lane * 8);
            bf16x8 wh1 = *(const bf16x8*)(cb + t * 2048 + 1 * 512 + lane * 8);
            bf16x8 wl0 = *(const bf16x8*)(cb + t * 2048 + 2 * 512 + lane * 8);
            bf16x8 wl1 = *(const bf16x8*)(cb + t * 2048 + 3 * 512 + lane * 8);
            const float cv = c2[ct * 16 + col];
            const int   kc = ct * 16 + col;

            f32x4 za[4];
#pragma unroll
            for (int m = 0; m < 4; ++m) za[m] = (f32x4){0.f, 0.f, 0.f, 0.f};
            // 6 rounds x 4 m-chains (dep distance 4 hides MFMA latency)
#pragma unroll
            for (int m = 0; m < 4; ++m)
                za[m] = __builtin_amdgcn_mfma_f32_16x16x32_bf16(zhi[m][0], wh0, za[m], 0, 0, 0);
#pragma unroll
            for (int m = 0; m < 4; ++m)
                za[m] = __builtin_amdgcn_mfma_f32_16x16x32_bf16(zhi[m][1], wh1, za[m], 0, 0, 0);
#pragma unroll
            for (int m = 0; m < 4; ++m)
                za[m] = __builtin_amdgcn_mfma_f32_16x16x32_bf16(zhi[m][0], wl0, za[m], 0, 0, 0);
#pragma unroll
            for (int m = 0; m < 4; ++m)
                za[m] = __builtin_amdgcn_mfma_f32_16x16x32_bf16(zhi[m][1], wl1, za[m], 0, 0, 0);
#pragma unroll
            for (int m = 0; m < 4; ++m)
                za[m] = __builtin_amdgcn_mfma_f32_16x16x32_bf16(zlo[m][0], wh0, za[m], 0, 0, 0);
#pragma unroll
            for (int m = 0; m < 4; ++m)
                za[m] = __builtin_amdgcn_mfma_f32_16x16x32_bf16(zlo[m][1], wh1, za[m], 0, 0, 0);

#pragma unroll
            for (int m = 0; m < 4; ++m)
#pragma unroll
                for (int r = 0; r < 4; ++r) {
                    float s = fmaf(-2.f, za[m][r], cv);
                    if (s < best[m][r]) { best[m][r] = s; bk[m][r] = kc; }
                }
        }
        __syncthreads();   // drains vmcnt (next chunk staged) + read-complete
    }

    // ---- merge argmin across the 16 code-column lanes (first-index tie-break) ----
#pragma unroll
    for (int off = 1; off < 16; off <<= 1) {
#pragma unroll
        for (int m = 0; m < 4; ++m)
#pragma unroll
            for (int r = 0; r < 4; ++r) {
                float ob = __shfl_xor(best[m][r], off, 64);
                int   ok = __shfl_xor(bk[m][r],   off, 64);
                if (ob < best[m][r] || (ob == best[m][r] && ok < bk[m][r])) {
                    best[m][r] = ob; bk[m][r] = ok;
                }
            }
    }

    // ---- epilogue per row-tile ----
    float commit = 0.f;
    const int srcl = (col >> 2) << 4;
    const int rsel = col & 3;
#pragma unroll
    for (int m = 0; m < 4; ++m) {
        int c0 = __shfl(bk[m][0], srcl, 64);
        int c1 = __shfl(bk[m][1], srcl, 64);
        int c2r = __shfl(bk[m][2], srcl, 64);
        int c3 = __shfl(bk[m][3], srcl, 64);
        int mybk = (rsel == 0) ? c0 : (rsel == 1) ? c1 : (rsel == 2) ? c2r : c3;

        const int hw0 = hwb + m * 16;
        if (lane < 16) idx_ws[(size_t)b * HWsz + hw0 + col] = mybk;

        float* qbase = out + (size_t)b * (Dd * HWsz) + hw0 + col;
#pragma unroll
        for (int s = 0; s < 2; ++s) {
            const float4* cw = reinterpret_cast<const float4*>(w + mybk * Dd + 32 * s + kg * 8);
            float4 p0 = cw[0], p1 = cw[1];
            float cbv[8] = {p0.x, p0.y, p0.z, p0.w, p1.x, p1.y, p1.z, p1.w};
#pragma unroll
            for (int j = 0; j < 8; ++j) {
                int   d  = 32 * s + kg * 8 + j;
                float zz = bf2f((unsigned short)zhi[m][s][j]) +
                           bf2f((unsigned short)zlo[m][s][j]);
                float cc = cbv[j];
                qbase[(size_t)d * HWsz] = zz + (cc - zz);
                float dd = zz - cc;
                commit = fmaf(dd, dd, commit);
            }
        }
    }

#pragma unroll
    for (int off = 32; off > 0; off >>= 1) commit += __shfl_down(commit, off, 64);

    __shared__ float red[2];
    if (lane == 0) red[wid] = commit;
    __syncthreads();
    if (threadIdx.x == 0) commit_ws[blockIdx.x] = red[0] + red[1];
}

// ---------------- phase 2: per-(b, d-pair) LDS accumulation, atomic-free out ----
// grid = 32 * 32 = 1024 blocks; each handles 2 d-planes of one image.
__global__ __launch_bounds__(256) void vq_stats(const float* __restrict__ z,
                                                const int* __restrict__ idx_ws,
                                                float* __restrict__ psum,
                                                float* __restrict__ pcnt) {
    const int b  = blockIdx.x >> 5;
    const int dp = blockIdx.x & 31;
    const int d0 = dp * 2;
    const bool docnt = (dp == 0);

    __shared__ float acc0[Kk], acc1[Kk], cnt[Kk];
    for (int i = threadIdx.x; i < Kk; i += 256) { acc0[i] = 0.f; acc1[i] = 0.f; cnt[i] = 0.f; }
    __syncthreads();

    const int4*   ip  = reinterpret_cast<const int4*>(idx_ws + (size_t)b * HWsz);
    const float4* zp0 = reinterpret_cast<const float4*>(z + ((size_t)b * Dd + d0) * HWsz);
    const float4* zp1 = reinterpret_cast<const float4*>(z + ((size_t)b * Dd + d0 + 1) * HWsz);
#pragma unroll
    for (int it = 0; it < 4; ++it) {
        int c4 = it * 256 + threadIdx.x;
        int4   k4 = ip[c4];
        float4 v0 = zp0[c4];
        float4 v1 = zp1[c4];
        atomicAdd(&acc0[k4.x], v0.x); atomicAdd(&acc0[k4.y], v0.y);
        atomicAdd(&acc0[k4.z], v0.z); atomicAdd(&acc0[k4.w], v0.w);
        atomicAdd(&acc1[k4.x], v1.x); atomicAdd(&acc1[k4.y], v1.y);
        atomicAdd(&acc1[k4.z], v1.z); atomicAdd(&acc1[k4.w], v1.w);
        if (docnt) {
            atomicAdd(&cnt[k4.x], 1.f); atomicAdd(&cnt[k4.y], 1.f);
            atomicAdd(&cnt[k4.z], 1.f); atomicAdd(&cnt[k4.w], 1.f);
        }
    }
    __syncthreads();

    // psum layout: [b][d][k]
    float* po = psum + ((size_t)b * Dd + d0) * Kk;
    for (int i = threadIdx.x; i < Kk; i += 256) { po[i] = acc0[i]; po[Kk + i] = acc1[i]; }
    if (docnt) {
        float* pc = pcnt + (size_t)b * Kk;
        for (int i = threadIdx.x; i < Kk; i += 256) pc[i] = cnt[i];
    }
}

// ---------------- phase 3: reduce partials over batch + losses ----------------
__global__ __launch_bounds__(256) void vq_reduce(const float* __restrict__ psum,
                                                 const float* __restrict__ pcnt,
                                                 const float* __restrict__ commit_ws,
                                                 float* __restrict__ out) {
    int t = blockIdx.x * 256 + threadIdx.x;   // 65536 threads (256 blocks)
    int k = t & 1023, d = t >> 10;
    float s = 0.f;
#pragma unroll
    for (int b = 0; b < NB; ++b)
        s += psum[((size_t)b * Dd + d) * Kk + k];
    out[QSIZE + 2 + Kk + (size_t)k * Dd + d] = s;
    if (t < Kk) {
        float c = 0.f;
#pragma unroll
        for (int b = 0; b < NB; ++b) c += pcnt[((size_t)b << 10) + t];
        out[QSIZE + 2 + t] = c;
    }

    if (blockIdx.x == 0) {
        float cs = 0.f;
        for (int i = threadIdx.x; i < DIST_BLOCKS; i += 256) cs += commit_ws[i];
#pragma unroll
        for (int off = 32; off > 0; off >>= 1) cs += __shfl_down(cs, off, 64);
        __shared__ float r2[4];
        const int lane = threadIdx.x & 63, wid = threadIdx.x >> 6;
        if (lane == 0) r2[wid] = cs;
        __syncthreads();
        if (threadIdx.x == 0) {
            float c = ((r2[0] + r2[1]) + (r2[2] + r2[3])) / (float)QSIZE;
            out[QSIZE]     = BETA_C * c;
            out[QSIZE + 1] = c;
        }
    }
}

extern "C" void kernel_launch(void* const* d_in, const int* in_sizes, int n_in,
                              void* d_out, int out_size, void* d_ws, size_t ws_size,
                              hipStream_t stream) {
    const float* z = (const float*)d_in[0];
    const float* w = (const float*)d_in[1];
    float* out = (float*)d_out;

    // ws layout (float offsets):
    // commit 0..1023 | c2 1024..2047 | whi (65536 us) | wlo (65536 us) |
    // idx (131072 int) | pcnt (32*1024) | psum (32*64*1024)
    float* commit_ws = (float*)d_ws;
    float* c2        = (float*)d_ws + 1024;
    unsigned short* whi = (unsigned short*)((float*)d_ws + 2048);
    unsigned short* wlo = whi + (Kk * Dd);
    int*   idx_ws = (int*)(wlo + (Kk * Dd));
    float* pcnt   = (float*)(idx_ws + NTOT);
    float* psum   = pcnt + (size_t)NB * Kk;

    vq_prep<<<(Kk * Dd) / 256, 256, 0, stream>>>(w, c2, whi, wlo);
    vq_dist<<<DIST_BLOCKS, 128, 0, stream>>>(z, w, c2, whi, wlo, out, commit_ws, idx_ws);
    vq_stats<<<NB * 32, 256, 0, stream>>>(z, idx_ws, psum, pcnt);
    vq_reduce<<<(Kk * Dd) / 256, 256, 0, stream>>>(psum, pcnt, commit_ws, out);
}